// Round 1
// baseline (43.507 us; speedup 1.0000x reference)
//
#include <hip/hip_runtime.h>
#include <math.h>

// Problem constants
#define NIMG 131072       // batch
#define NPIX 128          // 8x16 pixels per image
#define G2   2048         // main-kernel grid

// ws layout (floats):
//   [0    .. 1023]  W'[8][128]
//   [1024 .. 5119]  per-block partials (sum, sumsq) x G2
//   [5120]          alpha
//   [5128 .. 5135]  const[8]
// total ~20.6 KB

__device__ __forceinline__ float med3f(float a, float b, float c) {
  return __builtin_amdgcn_fmed3f(a, b, c);
}
__device__ __forceinline__ float min3f(float a, float b, float c) { return fminf(fminf(a, b), c); }
__device__ __forceinline__ float max3f(float a, float b, float c) { return fmaxf(fmaxf(a, b), c); }

// ---------------------------------------------------------------------------
// K1: fold shift + FC into W'[c][y*16+x].
// grid_sample samples output (i,j) at input pos (i - sy, j - sx), sy=yshift+0.5.
// y0(i) = i - dY (w=wy0), y1(i) = i - dY + 1 (w=wy1), dY = (sy>1)?2:1, wy1 = dY - sy.
// Input row y receives from output rows i = y+dY (wy0) and i = y+dY-1 (wy1).
__global__ void k_weights(const float* __restrict__ fc_w,
                          const float* __restrict__ xshift,
                          const float* __restrict__ yshift,
                          float* __restrict__ wp) {
  const int p = threadIdx.x;  // 0..127
  const int y = p >> 4, x = p & 15;
  const float sy = yshift[0] + 0.5f;
  const float sx = xshift[0] + 0.5f;
  const int dY = (sy > 1.0f) ? 2 : 1;
  const int dX = (sx > 1.0f) ? 2 : 1;
  const float wy1 = (float)dY - sy, wy0 = 1.0f - wy1;
  const float wx1 = (float)dX - sx, wx0 = 1.0f - wx1;

  const int   iys[2] = { y + dY - 1, y + dY };
  const float wys[2] = { wy1, wy0 };
  const int   jxs[2] = { x + dX - 1, x + dX };
  const float wxs[2] = { wx1, wx0 };

  #pragma unroll
  for (int c = 0; c < 8; ++c) {
    float acc = 0.0f;
    #pragma unroll
    for (int a = 0; a < 2; ++a) {
      if (iys[a] < 0 || iys[a] >= 8) continue;
      #pragma unroll
      for (int b = 0; b < 2; ++b) {
        if (jxs[b] < 0 || jxs[b] >= 16) continue;
        acc += wys[a] * wxs[b] * fc_w[c * 128 + iys[a] * 16 + jxs[b]];
      }
    }
    wp[c * 128 + p] = acc;
  }
}

// ---------------------------------------------------------------------------
// K2: main pass. 256 thr = 4 waves; each wave handles 2 images per iter
// (lanes 0-31 image A, 32-63 image B). Lane owns 4 consecutive pixels
// (row y = m>>2, cols X..X+3). LDS tile per image: 10x18 with zero border
// (col offset +1, row offset +1) for exact zero-padded 3x3 median.
__global__ __launch_bounds__(256) void k_main(const float* __restrict__ x,
                                              const float* __restrict__ wp,
                                              float* __restrict__ dotv,
                                              float* __restrict__ partial) {
  __shared__ float lds[8 * 184];   // 4 waves * 2 images, tile stride 184
  __shared__ float sred[8];
  const int tid = threadIdx.x;
  const int w   = tid >> 6;
  const int l   = tid & 63;
  const int ih  = l >> 5;          // which image of the pair
  const int m   = l & 31;
  const int y   = m >> 2;          // pixel row 0..7
  const int X   = (m & 3) << 2;    // pixel col base 0,4,8,12
  const int pbase = (y << 4) + X;
  float* tile = &lds[(w * 2 + ih) * 184];

  for (int i = tid; i < 8 * 184; i += 256) lds[i] = 0.0f;  // borders stay 0 forever

  // W' for this lane's 4 pixels, all 8 classes (loaded once)
  float wreg[8][4];
  #pragma unroll
  for (int c = 0; c < 8; ++c) {
    const float4 wv = *(const float4*)&wp[c * 128 + pbase];
    wreg[c][0] = wv.x; wreg[c][1] = wv.y; wreg[c][2] = wv.z; wreg[c][3] = wv.w;
  }

  float ssum = 0.0f, ssq = 0.0f;
  const int gw = blockIdx.x * 4 + w;
  const int wavesTotal = G2 * 4;
  // class this lane writes after the multi-value reduce
  const int c_l = ((l >> 4) & 1) * 4 + ((l >> 3) & 1) * 2 + ((l >> 2) & 1);

  __syncthreads();  // zero-init visible to all

  for (int pi = gw; pi < NIMG / 2; pi += wavesTotal) {
    const int img = 2 * pi + ih;
    const float4 v = *(const float4*)&x[img * 128 + pbase];
    float* wr = &tile[(y + 1) * 18 + X + 1];
    wr[0] = v.x; wr[1] = v.y; wr[2] = v.z; wr[3] = v.w;
    __syncthreads();

    // column sort3 for the 6 columns covering all 4 windows
    float lo[6], mi[6], hi[6];
    #pragma unroll
    for (int c6 = 0; c6 < 6; ++c6) {
      const float a = tile[(y + 0) * 18 + X + c6];
      const float b = tile[(y + 1) * 18 + X + c6];
      const float d = tile[(y + 2) * 18 + X + c6];
      lo[c6] = min3f(a, b, d);
      mi[c6] = med3f(a, b, d);
      hi[c6] = max3f(a, b, d);
    }

    float acc[8];
    #pragma unroll
    for (int c = 0; c < 8; ++c) acc[c] = 0.0f;

    #pragma unroll
    for (int k = 0; k < 4; ++k) {
      const float mx  = max3f(lo[k], lo[k + 1], lo[k + 2]);
      const float md  = med3f(mi[k], mi[k + 1], mi[k + 2]);
      const float mn  = min3f(hi[k], hi[k + 1], hi[k + 2]);
      const float med = med3f(mx, md, mn);  // exact lower-median of 9
      ssum += med;
      ssq = fmaf(med, med, ssq);
      #pragma unroll
      for (int c = 0; c < 8; ++c) acc[c] = fmaf(med, wreg[c][k], acc[c]);
    }

    // multi-value butterfly: 8 accs over 32 lanes -> 1 value/lane
    const bool b16 = (l & 16) != 0;
    float r4[4];
    #pragma unroll
    for (int j = 0; j < 4; ++j) {
      const float send = b16 ? acc[j] : acc[4 + j];
      const float keep = b16 ? acc[4 + j] : acc[j];
      r4[j] = keep + __shfl_xor(send, 16, 64);
    }
    const bool b8 = (l & 8) != 0;
    float r2[2];
    #pragma unroll
    for (int j = 0; j < 2; ++j) {
      const float send = b8 ? r4[j] : r4[2 + j];
      const float keep = b8 ? r4[2 + j] : r4[j];
      r2[j] = keep + __shfl_xor(send, 8, 64);
    }
    const bool b4 = (l & 4) != 0;
    {
      const float send = b4 ? r2[0] : r2[1];
      const float keep = b4 ? r2[1] : r2[0];
      float r = keep + __shfl_xor(send, 4, 64);
      r += __shfl_xor(r, 2, 64);
      r += __shfl_xor(r, 1, 64);
      if ((l & 3) == 0) dotv[img * 8 + c_l] = r;  // 16 lanes -> 64 contiguous bytes
    }
    __syncthreads();  // WAR: reads done before next iter's writes
  }

  // deterministic per-block stats
  #pragma unroll
  for (int off = 32; off; off >>= 1) {
    ssum += __shfl_xor(ssum, off, 64);
    ssq  += __shfl_xor(ssq,  off, 64);
  }
  if (l == 0) { sred[w] = ssum; sred[4 + w] = ssq; }
  __syncthreads();
  if (tid == 0) partial[2 * blockIdx.x]     = (sred[0] + sred[1]) + (sred[2] + sred[3]);
  if (tid == 1) partial[2 * blockIdx.x + 1] = (sred[4] + sred[5]) + (sred[6] + sred[7]);
}

// ---------------------------------------------------------------------------
// K3: finalize scalars. alpha = bnw * rsqrt(var+eps); const[c] = beta*sum(W'[c]) + fc_b[c]
__global__ void k_final(const float* __restrict__ wp, const float* __restrict__ partial,
                        const float* __restrict__ fcb, const float* __restrict__ bnw,
                        const float* __restrict__ bnb, float* __restrict__ scal) {
  __shared__ float red[8];
  __shared__ float beta_sh;
  const int tid = threadIdx.x;
  float s = 0.0f, q = 0.0f;
  for (int i = tid; i < G2; i += 256) { s += partial[2 * i]; q += partial[2 * i + 1]; }
  #pragma unroll
  for (int off = 32; off; off >>= 1) { s += __shfl_xor(s, off, 64); q += __shfl_xor(q, off, 64); }
  const int w = tid >> 6, l = tid & 63;
  if (l == 0) { red[w] = s; red[4 + w] = q; }
  __syncthreads();
  if (tid == 0) {
    const float S = (red[0] + red[1]) + (red[2] + red[3]);
    const float Q = (red[4] + red[5]) + (red[6] + red[7]);
    const float N = 16777216.0f;  // 131072*128
    const float mm = S / N;
    const float vv = Q / N - mm * mm;
    const float a = bnw[0] / sqrtf(vv + 1e-5f);
    scal[0] = a;
    beta_sh = bnb[0] - mm * a;
  }
  __syncthreads();
  if (tid < 8) {
    float wsum = 0.0f;
    for (int p = 0; p < 128; ++p) wsum += wp[tid * 128 + p];
    scal[8 + tid] = beta_sh * wsum + fcb[tid];
  }
}

// ---------------------------------------------------------------------------
// K4: out = alpha*out + const[c], in place over [131072][8] floats, float4 lanes
__global__ __launch_bounds__(256) void k_scale(float* __restrict__ out,
                                               const float* __restrict__ scal) {
  const int i = blockIdx.x * 256 + threadIdx.x;  // 262144 threads x float4
  const float a = scal[0];
  const float4 c0 = *(const float4*)&scal[8];
  const float4 c1 = *(const float4*)&scal[12];
  float4* o4 = (float4*)out;
  float4 v = o4[i];
  const float4 c = (i & 1) ? c1 : c0;
  v.x = fmaf(a, v.x, c.x);
  v.y = fmaf(a, v.y, c.y);
  v.z = fmaf(a, v.z, c.z);
  v.w = fmaf(a, v.w, c.w);
  o4[i] = v;
}

// ---------------------------------------------------------------------------
extern "C" void kernel_launch(void* const* d_in, const int* in_sizes, int n_in,
                              void* d_out, int out_size, void* d_ws, size_t ws_size,
                              hipStream_t stream) {
  const float* x   = (const float*)d_in[0];
  const float* bnw = (const float*)d_in[1];
  const float* bnb = (const float*)d_in[2];
  const float* xs  = (const float*)d_in[3];
  const float* ys  = (const float*)d_in[4];
  const float* fcw = (const float*)d_in[5];
  const float* fcb = (const float*)d_in[6];
  float* out = (float*)d_out;
  float* ws  = (float*)d_ws;

  float* wp      = ws;           // 1024 floats
  float* partial = ws + 1024;    // 2*G2 floats
  float* scal    = ws + 5120;    // alpha @0, const[8] @8..15

  hipLaunchKernelGGL(k_weights, dim3(1),    dim3(128), 0, stream, fcw, xs, ys, wp);
  hipLaunchKernelGGL(k_main,    dim3(G2),   dim3(256), 0, stream, x, wp, out, partial);
  hipLaunchKernelGGL(k_final,   dim3(1),    dim3(256), 0, stream, wp, partial, fcb, bnw, bnb, scal);
  hipLaunchKernelGGL(k_scale,   dim3(1024), dim3(256), 0, stream, out, scal);
}

// Round 3
// 40.691 us; speedup vs baseline: 1.0692x; 1.0692x over previous
//
#include <hip/hip_runtime.h>
#include <math.h>

#define NIMG 131072
#define NBLK 512   // k_main grid: 512 blocks x 256 threads = 1 thread per image

// ws layout (floats): [0..1023] W'[8][128] ; [1024..1031] wsum[8] ; [1040..2063] partial[1024]

__device__ __forceinline__ float med3f(float a, float b, float c) {
  return __builtin_amdgcn_fmed3f(a, b, c);
}
__device__ __forceinline__ float min3f(float a, float b, float c) { return fminf(fminf(a, b), c); }
__device__ __forceinline__ float max3f(float a, float b, float c) { return fmaxf(fmaxf(a, b), c); }

// ---------------------------------------------------------------------------
// K1: fold shift + FC into W'[c][p], plus per-class sums wsum[c] (validated in R1).
__global__ void k_weights(const float* __restrict__ fc_w,
                          const float* __restrict__ xshift,
                          const float* __restrict__ yshift,
                          float* __restrict__ wp,
                          float* __restrict__ wsum) {
  const int p = threadIdx.x;  // 0..127
  const int y = p >> 4, x = p & 15;
  const float sy = yshift[0] + 0.5f;
  const float sx = xshift[0] + 0.5f;
  const int dY = (sy > 1.0f) ? 2 : 1;
  const int dX = (sx > 1.0f) ? 2 : 1;
  const float wy1 = (float)dY - sy, wy0 = 1.0f - wy1;
  const float wx1 = (float)dX - sx, wx0 = 1.0f - wx1;

  const int   iys[2] = { y + dY - 1, y + dY };
  const float wys[2] = { wy1, wy0 };
  const int   jxs[2] = { x + dX - 1, x + dX };
  const float wxs[2] = { wx1, wx0 };

  float v[8];
  #pragma unroll
  for (int c = 0; c < 8; ++c) {
    float acc = 0.0f;
    #pragma unroll
    for (int a = 0; a < 2; ++a) {
      if (iys[a] < 0 || iys[a] >= 8) continue;
      #pragma unroll
      for (int b = 0; b < 2; ++b) {
        if (jxs[b] < 0 || jxs[b] >= 16) continue;
        acc += wys[a] * wxs[b] * fc_w[c * 128 + iys[a] * 16 + jxs[b]];
      }
    }
    wp[c * 128 + p] = acc;
    v[c] = acc;
  }

  __shared__ float part[2][8];
  const int w = p >> 6, l = p & 63;
  #pragma unroll
  for (int c = 0; c < 8; ++c) {
    #pragma unroll
    for (int off = 32; off; off >>= 1) v[c] += __shfl_xor(v[c], off, 64);
  }
  if (l == 0) {
    #pragma unroll
    for (int c = 0; c < 8; ++c) part[w][c] = v[c];
  }
  __syncthreads();
  if (p < 8) wsum[p] = part[0][p] + part[1][p];
}

// ---------------------------------------------------------------------------
// K2: one thread per image, all in registers. Streaming 3x3 lower-median
// (rotating 4-row window, prefetch distance 2), dot with W' via wave-uniform
// scalar loads, per-block (sum, sumsq) partials. Writes RAW dots to out.
__global__ __launch_bounds__(256, 2) void k_main(const float* __restrict__ x,
                                                 const float* __restrict__ wp,
                                                 float* __restrict__ out,
                                                 float* __restrict__ partial) {
  __shared__ float sred[8];
  const int tid = threadIdx.x;
  const int w = tid >> 6, l = tid & 63;
  const int img = blockIdx.x * 256 + tid;
  const float* __restrict__ xi = x + (size_t)img * 128;

  float rows[4][16];
  #pragma unroll
  for (int rr = 0; rr < 2; ++rr)
    #pragma unroll
    for (int q = 0; q < 4; ++q)
      *(float4*)&rows[rr][q * 4] = *(const float4*)&xi[rr * 16 + q * 4];

  float acc[8];
  #pragma unroll
  for (int c = 0; c < 8; ++c) acc[c] = 0.0f;
  float ssum = 0.0f, ssq = 0.0f;

  #pragma unroll
  for (int r = 0; r < 8; ++r) {
    if (r < 6) {
      #pragma unroll
      for (int q = 0; q < 4; ++q)
        *(float4*)&rows[(r + 2) & 3][q * 4] = *(const float4*)&xi[(r + 2) * 16 + q * 4];
    }
    // vertical sort3 per column (zero rows outside [0,7])
    float lo[16], mi[16], hi[16];
    #pragma unroll
    for (int c = 0; c < 16; ++c) {
      const float a = (r == 0) ? 0.0f : rows[(r - 1) & 3][c];
      const float b = rows[r & 3][c];
      const float d = (r == 7) ? 0.0f : rows[(r + 1) & 3][c];
      lo[c] = min3f(a, b, d);
      mi[c] = med3f(a, b, d);
      hi[c] = max3f(a, b, d);
    }
    // horizontal combine (zero cols outside [0,15]) + stats + dot
    #pragma unroll
    for (int j = 0; j < 16; ++j) {
      const float l0 = (j == 0) ? 0.0f : lo[j - 1];
      const float l2 = (j == 15) ? 0.0f : lo[j + 1];
      const float m0 = (j == 0) ? 0.0f : mi[j - 1];
      const float m2 = (j == 15) ? 0.0f : mi[j + 1];
      const float h0 = (j == 0) ? 0.0f : hi[j - 1];
      const float h2 = (j == 15) ? 0.0f : hi[j + 1];
      const float mx = max3f(l0, lo[j], l2);
      const float md = med3f(m0, mi[j], m2);
      const float mn = min3f(h0, hi[j], h2);
      const float med = med3f(mx, md, mn);  // exact lower-median of 9
      ssum += med;
      ssq = fmaf(med, med, ssq);
      #pragma unroll
      for (int c = 0; c < 8; ++c)
        acc[c] = fmaf(med, wp[c * 128 + r * 16 + j], acc[c]);  // uniform -> s_load
    }
  }

  // raw dots to out (scaled in k_scale)
  float4* o4 = (float4*)&out[(size_t)img * 8];
  o4[0] = make_float4(acc[0], acc[1], acc[2], acc[3]);
  o4[1] = make_float4(acc[4], acc[5], acc[6], acc[7]);

  // per-block stats
  #pragma unroll
  for (int off = 32; off; off >>= 1) {
    ssum += __shfl_xor(ssum, off, 64);
    ssq  += __shfl_xor(ssq,  off, 64);
  }
  if (l == 0) { sred[w] = ssum; sred[4 + w] = ssq; }
  __syncthreads();
  if (tid == 0) partial[2 * blockIdx.x]     = (sred[0] + sred[1]) + (sred[2] + sred[3]);
  if (tid == 1) partial[2 * blockIdx.x + 1] = (sred[4] + sred[5]) + (sred[6] + sred[7]);
}

// ---------------------------------------------------------------------------
// K3: every block redundantly reduces partial[1024] (L2-hot, deterministic),
// computes alpha/beta, then scales its slice of out in place:
// out = alpha*dot + (beta*wsum[c] + fcb[c]).
__global__ __launch_bounds__(256) void k_scale(float* __restrict__ out,
                                               const float* __restrict__ partial,
                                               const float* __restrict__ wsum8,
                                               const float* __restrict__ fcb,
                                               const float* __restrict__ bnw,
                                               const float* __restrict__ bnb) {
  __shared__ float sred[8];
  __shared__ float fin[2];
  const int tid = threadIdx.x;
  const int w = tid >> 6, l = tid & 63;

  float s = partial[2 * tid]     + partial[2 * (tid + 256)];
  float q = partial[2 * tid + 1] + partial[2 * (tid + 256) + 1];
  #pragma unroll
  for (int off = 32; off; off >>= 1) {
    s += __shfl_xor(s, off, 64);
    q += __shfl_xor(q, off, 64);
  }
  if (l == 0) { sred[w] = s; sred[4 + w] = q; }
  __syncthreads();
  if (tid == 0) {
    const float S = (sred[0] + sred[1]) + (sred[2] + sred[3]);
    const float Q = (sred[4] + sred[5]) + (sred[6] + sred[7]);
    const float N = 16777216.0f;  // 131072*128
    const float mm = S / N;
    const float vv = Q / N - mm * mm;
    const float a = bnw[0] / sqrtf(vv + 1e-5f);
    fin[0] = a;
    fin[1] = bnb[0] - mm * a;
  }
  __syncthreads();
  const float alpha = fin[0], beta = fin[1];

  const float4 ws0 = *(const float4*)&wsum8[0];
  const float4 ws1 = *(const float4*)&wsum8[4];
  const float4 fb0 = *(const float4*)&fcb[0];
  const float4 fb1 = *(const float4*)&fcb[4];

  const int i = blockIdx.x * 256 + tid;  // 262144 float4 covering [131072][8]
  const bool hi = (i & 1) != 0;
  const float4 wsv = hi ? ws1 : ws0;
  const float4 fbv = hi ? fb1 : fb0;
  float4* o4 = (float4*)out;
  float4 v = o4[i];
  v.x = fmaf(alpha, v.x, fmaf(beta, wsv.x, fbv.x));
  v.y = fmaf(alpha, v.y, fmaf(beta, wsv.y, fbv.y));
  v.z = fmaf(alpha, v.z, fmaf(beta, wsv.z, fbv.z));
  v.w = fmaf(alpha, v.w, fmaf(beta, wsv.w, fbv.w));
  o4[i] = v;
}

// ---------------------------------------------------------------------------
extern "C" void kernel_launch(void* const* d_in, const int* in_sizes, int n_in,
                              void* d_out, int out_size, void* d_ws, size_t ws_size,
                              hipStream_t stream) {
  const float* x   = (const float*)d_in[0];
  const float* bnw = (const float*)d_in[1];
  const float* bnb = (const float*)d_in[2];
  const float* xs  = (const float*)d_in[3];
  const float* ys  = (const float*)d_in[4];
  const float* fcw = (const float*)d_in[5];
  const float* fcb = (const float*)d_in[6];
  float* out = (float*)d_out;
  float* ws  = (float*)d_ws;

  float* wp      = ws;          // 1024
  float* wsum    = ws + 1024;   // 8
  float* partial = ws + 1040;   // 1024

  hipLaunchKernelGGL(k_weights, dim3(1),    dim3(128), 0, stream, fcw, xs, ys, wp, wsum);
  hipLaunchKernelGGL(k_main,    dim3(NBLK), dim3(256), 0, stream, x, wp, out, partial);
  hipLaunchKernelGGL(k_scale,   dim3(1024), dim3(256), 0, stream, out, partial, wsum, fcb, bnw, bnb);
}

// Round 4
// 32.414 us; speedup vs baseline: 1.3422x; 1.2554x over previous
//
#include <hip/hip_runtime.h>
#include <math.h>

#define NIMG 131072
#define NBLK 512   // k_main grid: 512 blocks x 256 threads = 1 thread per image

// ws layout (floats): [0..1023] partial[1024] (sum,sumsq per k_main block)

__device__ __forceinline__ float med3f(float a, float b, float c) {
  return __builtin_amdgcn_fmed3f(a, b, c);
}
__device__ __forceinline__ float min3f(float a, float b, float c) { return fminf(fminf(a, b), c); }
__device__ __forceinline__ float max3f(float a, float b, float c) { return fmaxf(fmaxf(a, b), c); }

// ---------------------------------------------------------------------------
// Fold shift + FC into W'[c] for pixel p (math validated on HW in R1/R3).
// grid_sample: output (i,j) samples input (i-sy, j-sx), sy=yshift+0.5.
// Input pixel (y,x) receives from output rows y+dY-1 (w=wy1) and y+dY (w=wy0).
__device__ __forceinline__ void fold_weights(int p, const float* __restrict__ fc_w,
                                             float sx, float sy, float* __restrict__ w8) {
  const int y = p >> 4, x = p & 15;
  const int dY = (sy > 1.0f) ? 2 : 1;
  const int dX = (sx > 1.0f) ? 2 : 1;
  const float wy1 = (float)dY - sy, wy0 = 1.0f - wy1;
  const float wx1 = (float)dX - sx, wx0 = 1.0f - wx1;
  const int   iys[2] = { y + dY - 1, y + dY };
  const float wys[2] = { wy1, wy0 };
  const int   jxs[2] = { x + dX - 1, x + dX };
  const float wxs[2] = { wx1, wx0 };
  #pragma unroll
  for (int c = 0; c < 8; ++c) {
    float acc = 0.0f;
    #pragma unroll
    for (int a = 0; a < 2; ++a) {
      if (iys[a] < 0 || iys[a] >= 8) continue;
      #pragma unroll
      for (int b = 0; b < 2; ++b) {
        if (jxs[b] < 0 || jxs[b] >= 16) continue;
        acc += wys[a] * wxs[b] * fc_w[c * 128 + iys[a] * 16 + jxs[b]];
      }
    }
    w8[c] = acc;
  }
}

// ---------------------------------------------------------------------------
// K1: one thread per image, medians in registers; weights from LDS via
// wave-uniform ds_read_b128 broadcasts (in-order lgkmcnt, no scalar-load
// drain serialization). Writes RAW dots to out, (sum,sumsq) partials to ws.
__global__ __launch_bounds__(256, 2) void k_main(const float* __restrict__ x,
                                                 const float* __restrict__ fcw,
                                                 const float* __restrict__ xs,
                                                 const float* __restrict__ ys,
                                                 float* __restrict__ out,
                                                 float* __restrict__ partial) {
  __shared__ float wlds[128 * 8];  // pixel-major: wlds[p*8+c]
  __shared__ float sred[8];
  const int tid = threadIdx.x;
  const int w = tid >> 6, l = tid & 63;
  const int img = blockIdx.x * 256 + tid;
  const float* __restrict__ xi = x + (size_t)img * 128;

  // start input prologue loads first (independent of weight fold)
  float rows[4][16];
  #pragma unroll
  for (int rr = 0; rr < 2; ++rr)
    #pragma unroll
    for (int q = 0; q < 4; ++q)
      *(float4*)&rows[rr][q * 4] = *(const float4*)&xi[rr * 16 + q * 4];

  // per-block W' fold into LDS (threads 0..127)
  if (tid < 128) {
    float w8[8];
    fold_weights(tid, fcw, xs[0] + 0.5f, ys[0] + 0.5f, w8);
    #pragma unroll
    for (int c = 0; c < 8; ++c) wlds[tid * 8 + c] = w8[c];
  }
  __syncthreads();

  float acc[8];
  #pragma unroll
  for (int c = 0; c < 8; ++c) acc[c] = 0.0f;
  float ssum = 0.0f, ssq = 0.0f;

  #pragma unroll
  for (int r = 0; r < 8; ++r) {
    if (r < 6) {
      #pragma unroll
      for (int q = 0; q < 4; ++q)
        *(float4*)&rows[(r + 2) & 3][q * 4] = *(const float4*)&xi[(r + 2) * 16 + q * 4];
    }
    // vertical sort3 per column (zero rows outside [0,7])
    float lo[16], mi[16], hi[16];
    #pragma unroll
    for (int c = 0; c < 16; ++c) {
      const float a = (r == 0) ? 0.0f : rows[(r - 1) & 3][c];
      const float b = rows[r & 3][c];
      const float d = (r == 7) ? 0.0f : rows[(r + 1) & 3][c];
      lo[c] = min3f(a, b, d);
      mi[c] = med3f(a, b, d);
      hi[c] = max3f(a, b, d);
    }
    // horizontal combine (zero cols outside [0,15]) + stats + dot
    #pragma unroll
    for (int j = 0; j < 16; ++j) {
      const float l0 = (j == 0) ? 0.0f : lo[j - 1];
      const float l2 = (j == 15) ? 0.0f : lo[j + 1];
      const float m0 = (j == 0) ? 0.0f : mi[j - 1];
      const float m2 = (j == 15) ? 0.0f : mi[j + 1];
      const float h0 = (j == 0) ? 0.0f : hi[j - 1];
      const float h2 = (j == 15) ? 0.0f : hi[j + 1];
      const float mx = max3f(l0, lo[j], l2);
      const float md = med3f(m0, mi[j], m2);
      const float mn = min3f(h0, hi[j], h2);
      const float med = med3f(mx, md, mn);  // exact lower-median of 9
      ssum += med;
      ssq = fmaf(med, med, ssq);
      const float4 w0 = *(const float4*)&wlds[(r * 16 + j) * 8];      // broadcast
      const float4 w1 = *(const float4*)&wlds[(r * 16 + j) * 8 + 4];  // broadcast
      acc[0] = fmaf(med, w0.x, acc[0]);
      acc[1] = fmaf(med, w0.y, acc[1]);
      acc[2] = fmaf(med, w0.z, acc[2]);
      acc[3] = fmaf(med, w0.w, acc[3]);
      acc[4] = fmaf(med, w1.x, acc[4]);
      acc[5] = fmaf(med, w1.y, acc[5]);
      acc[6] = fmaf(med, w1.z, acc[6]);
      acc[7] = fmaf(med, w1.w, acc[7]);
    }
  }

  // raw dots to out (scaled in k_scale)
  float4* o4 = (float4*)&out[(size_t)img * 8];
  o4[0] = make_float4(acc[0], acc[1], acc[2], acc[3]);
  o4[1] = make_float4(acc[4], acc[5], acc[6], acc[7]);

  // per-block stats
  #pragma unroll
  for (int off = 32; off; off >>= 1) {
    ssum += __shfl_xor(ssum, off, 64);
    ssq  += __shfl_xor(ssq,  off, 64);
  }
  if (l == 0) { sred[w] = ssum; sred[4 + w] = ssq; }
  __syncthreads();
  if (tid == 0) partial[2 * blockIdx.x]     = (sred[0] + sred[1]) + (sred[2] + sred[3]);
  if (tid == 1) partial[2 * blockIdx.x + 1] = (sred[4] + sred[5]) + (sred[6] + sred[7]);
}

// ---------------------------------------------------------------------------
// K2: every block redundantly reduces partial[1024] (L2-hot, deterministic),
// recomputes the W' fold for per-class sums, then scales its slice of out
// in place: out = alpha*dot + (beta*wsum[c] + fcb[c]).
__global__ __launch_bounds__(256) void k_scale(float* __restrict__ out,
                                               const float* __restrict__ partial,
                                               const float* __restrict__ fcw,
                                               const float* __restrict__ xs,
                                               const float* __restrict__ ys,
                                               const float* __restrict__ fcb,
                                               const float* __restrict__ bnw,
                                               const float* __restrict__ bnb) {
  __shared__ float sred[8];
  __shared__ float wred[4][8];
  __shared__ float fin[2];
  const int tid = threadIdx.x;
  const int w = tid >> 6, l = tid & 63;

  // batch stats
  float s = partial[2 * tid]     + partial[2 * (tid + 256)];
  float q = partial[2 * tid + 1] + partial[2 * (tid + 256) + 1];
  #pragma unroll
  for (int off = 32; off; off >>= 1) {
    s += __shfl_xor(s, off, 64);
    q += __shfl_xor(q, off, 64);
  }

  // redundant W' fold for per-class sums (threads 0..127 contribute)
  float v[8];
  if (tid < 128) {
    fold_weights(tid, fcw, xs[0] + 0.5f, ys[0] + 0.5f, v);
  } else {
    #pragma unroll
    for (int c = 0; c < 8; ++c) v[c] = 0.0f;
  }
  #pragma unroll
  for (int c = 0; c < 8; ++c) {
    #pragma unroll
    for (int off = 32; off; off >>= 1) v[c] += __shfl_xor(v[c], off, 64);
  }

  if (l == 0) {
    sred[w] = s; sred[4 + w] = q;
    #pragma unroll
    for (int c = 0; c < 8; ++c) wred[w][c] = v[c];
  }
  __syncthreads();
  if (tid == 0) {
    const float S = (sred[0] + sred[1]) + (sred[2] + sred[3]);
    const float Q = (sred[4] + sred[5]) + (sred[6] + sred[7]);
    const float N = 16777216.0f;  // 131072*128
    const float mm = S / N;
    const float vv = Q / N - mm * mm;
    const float a = bnw[0] / sqrtf(vv + 1e-5f);
    fin[0] = a;
    fin[1] = bnb[0] - mm * a;
  }
  __syncthreads();
  const float alpha = fin[0], beta = fin[1];

  const int i = blockIdx.x * 256 + tid;  // 262144 float4 covering [131072][8]
  const int g = (i & 1) ? 4 : 0;
  float4 cv;
  cv.x = fmaf(beta, (wred[0][g + 0] + wred[1][g + 0]) + (wred[2][g + 0] + wred[3][g + 0]), fcb[g + 0]);
  cv.y = fmaf(beta, (wred[0][g + 1] + wred[1][g + 1]) + (wred[2][g + 1] + wred[3][g + 1]), fcb[g + 1]);
  cv.z = fmaf(beta, (wred[0][g + 2] + wred[1][g + 2]) + (wred[2][g + 2] + wred[3][g + 2]), fcb[g + 2]);
  cv.w = fmaf(beta, (wred[0][g + 3] + wred[1][g + 3]) + (wred[2][g + 3] + wred[3][g + 3]), fcb[g + 3]);

  float4* o4 = (float4*)out;
  float4 ov = o4[i];
  ov.x = fmaf(alpha, ov.x, cv.x);
  ov.y = fmaf(alpha, ov.y, cv.y);
  ov.z = fmaf(alpha, ov.z, cv.z);
  ov.w = fmaf(alpha, ov.w, cv.w);
  o4[i] = ov;
}

// ---------------------------------------------------------------------------
extern "C" void kernel_launch(void* const* d_in, const int* in_sizes, int n_in,
                              void* d_out, int out_size, void* d_ws, size_t ws_size,
                              hipStream_t stream) {
  const float* x   = (const float*)d_in[0];
  const float* bnw = (const float*)d_in[1];
  const float* bnb = (const float*)d_in[2];
  const float* xs  = (const float*)d_in[3];
  const float* ys  = (const float*)d_in[4];
  const float* fcw = (const float*)d_in[5];
  const float* fcb = (const float*)d_in[6];
  float* out = (float*)d_out;
  float* ws  = (float*)d_ws;

  float* partial = ws;  // 1024 floats

  hipLaunchKernelGGL(k_main,  dim3(NBLK), dim3(256), 0, stream, x, fcw, xs, ys, out, partial);
  hipLaunchKernelGGL(k_scale, dim3(1024), dim3(256), 0, stream, out, partial, fcw, xs, ys, fcb, bnw, bnb);
}